// Round 1
// baseline (2965.648 us; speedup 1.0000x reference)
//
#include <hip/hip_runtime.h>
#include <cstddef>

#define NT   8192   // time steps
#define RC   128    // columns
#define SX   64     // state dim
#define SU   4      // inputs
#define SY   4      // outputs
#define LCH  64     // chunk length
#define CCH  128    // chunks = NT/LCH
#define AUG  68     // SX+SY

// workspace layout (float offsets)
#define OFF_MST   0                     // 7*4096 = 28672  Mst[s][j*64+i] = (A^(64*2^s))[i][j]
#define OFF_AYTQ  28672                 // 64*4*20 = 5120
#define OFF_BUTQ  33792                 // 4*4*20  = 320
#define OFF_KT    34112                 // 256*64  = 16384  Kt[p*64+i] = Khat[i][p]
#define OFF_V0    51200                 // 128*64*128 = 1048576
#define OFF_V1    (51200 + 1048576)

static __device__ __forceinline__ int rfl(int x) { return __builtin_amdgcn_readfirstlane(x); }

// square a 64x64 matrix (flat [a*64+b]); works for transposed storage too since (MM)^T=(M^T)(M^T)
__device__ void matsq_block(const float* __restrict__ Min, float* __restrict__ Mout)
{
  __shared__ float P[64*65];
  const int tid = threadIdx.x;
  for (int e = tid; e < 4096; e += 256) P[(e>>6)*65 + (e&63)] = Min[e];
  __syncthreads();
  const int it = tid >> 4, jt = tid & 15;
  float acc[4][4] = {};
  for (int k = 0; k < 64; k++) {
    float a[4], b[4];
    #pragma unroll
    for (int ii = 0; ii < 4; ii++) a[ii] = P[(it*4+ii)*65 + k];
    #pragma unroll
    for (int jj = 0; jj < 4; jj++) b[jj] = P[k*65 + jt*4 + jj];
    #pragma unroll
    for (int ii = 0; ii < 4; ii++)
      #pragma unroll
      for (int jj = 0; jj < 4; jj++) acc[ii][jj] += a[ii]*b[jj];
  }
  #pragma unroll
  for (int ii = 0; ii < 4; ii++)
    #pragma unroll
    for (int jj = 0; jj < 4; jj++) Mout[(it*4+ii)*64 + jt*4 + jj] = acc[ii][jj];
}

// one block: A^64 (6 squarings), Khat (doubling), AYtq/Butq packed coefficient tables
__global__ __launch_bounds__(256) void k_setup(const float* __restrict__ A,
                                               const float* __restrict__ Bu,
                                               const float* __restrict__ Cy,
                                               const float* __restrict__ Dyu,
                                               float* __restrict__ ws)
{
  __shared__ float PA[64*65];
  __shared__ float PB[64*65];
  __shared__ float T[256*68];   // Khat columns, col-major: T[p*68+i]
  const int tid = threadIdx.x;
  float* Mst  = ws + OFF_MST;
  float* AYtq = ws + OFF_AYTQ;
  float* Butq = ws + OFF_BUTQ;
  float* Kt   = ws + OFF_KT;

  for (int e = tid; e < 4096; e += 256) PA[(e>>6)*65 + (e&63)] = A[e];
  // T rightmost 4 cols = B_u
  for (int e = tid; e < 256; e += 256) T[(252 + (e&3))*68 + (e>>2)] = Bu[e];
  // packed augmented [A;C] transposed, per-q 20-padded: AYtq[(j*4+q)*20+jj] = row(17q+jj), col j
  for (int e = tid; e < 64*4*20; e += 256) {
    int jj = e % 20; int qj = e / 20; int q = qj & 3; int j = qj >> 2; int i = q*17 + jj;
    float v = 0.f;
    if (jj < 17) v = (i < SX) ? A[i*64 + j] : Cy[(i-SX)*64 + j];
    AYtq[e] = v;
  }
  // packed [B;D]: Butq[(ch*4+q)*20+jj]
  for (int e = tid; e < 4*4*20; e += 256) {
    int jj = e % 20; int cq = e / 20; int q = cq & 3; int ch = cq >> 2; int i = q*17 + jj;
    float v = 0.f;
    if (jj < 17) v = (i < SX) ? Bu[i*4 + ch] : Dyu[(i-SX)*4 + ch];
    Butq[e] = v;
  }
  __syncthreads();

  float* P = PA; float* Q = PB;
  int w = 4;
  for (int m = 0; m < 6; m++) {
    // doubling: T cols [256-2w,256-w) = P @ T cols [256-w,256)   (P = A^(2^m))
    const int bin = 256 - w, bout = 256 - 2*w;
    for (int o = tid; o < w*64; o += 256) {
      const int pc = o >> 6, i = o & 63;
      float acc = 0.f;
      for (int k = 0; k < 64; k++) acc += P[i*65 + k] * T[(bin+pc)*68 + k];
      T[(bout+pc)*68 + i] = acc;
    }
    // square P -> Q
    {
      const int it = tid >> 4, jt = tid & 15;
      float acc[4][4] = {};
      for (int k = 0; k < 64; k++) {
        float a[4], b[4];
        #pragma unroll
        for (int ii = 0; ii < 4; ii++) a[ii] = P[(it*4+ii)*65 + k];
        #pragma unroll
        for (int jj = 0; jj < 4; jj++) b[jj] = P[k*65 + jt*4 + jj];
        #pragma unroll
        for (int ii = 0; ii < 4; ii++)
          #pragma unroll
          for (int jj = 0; jj < 4; jj++) acc[ii][jj] += a[ii]*b[jj];
      }
      #pragma unroll
      for (int ii = 0; ii < 4; ii++)
        #pragma unroll
        for (int jj = 0; jj < 4; jj++) Q[(it*4+ii)*65 + jt*4 + jj] = acc[ii][jj];
    }
    __syncthreads();
    float* tmp = P; P = Q; Q = tmp;
    w <<= 1;
  }
  // P = A^64; write transposed Mst[0], and Kt
  for (int e = tid; e < 4096; e += 256) { int j = e >> 6, i = e & 63; Mst[j*64 + i] = P[i*65 + j]; }
  for (int e = tid; e < 16384; e += 256) { int p = e >> 6, i = e & 63; Kt[e] = T[p*68 + i]; }
}

// w_b = Khat @ U_b for all chunks; block 256 fuses Mst[1] = Mst[0]^2
__global__ __launch_bounds__(256) void k_contrib(const float* __restrict__ u,
                                                 const float* __restrict__ Kt,
                                                 float* __restrict__ V0,
                                                 const float* __restrict__ sq_in,
                                                 float* __restrict__ sq_out)
{
  if (blockIdx.x == 256) { matsq_block(sq_in, sq_out); return; }
  const int b = blockIdx.x >> 1, h = blockIdx.x & 1;
  const int tid = threadIdx.x;
  const int q = rfl(tid >> 6);
  const int r = tid & 63;
  const int gr = h*64 + r;
  float acc[16] = {};
  const float* ub = u + (size_t)b*256*RC + gr;
  for (int p = 0; p < 256; p++) {
    const float up = ub[(size_t)p*RC];
    const float* kt = Kt + p*64 + q*16;
    #pragma unroll
    for (int jj = 0; jj < 16; jj++) acc[jj] += kt[jj] * up;
  }
  float* wv = V0 + ((size_t)b*SX + q*16)*RC + gr;
  #pragma unroll
  for (int jj = 0; jj < 16; jj++) wv[(size_t)jj*RC] = acc[jj];
}

// Hillis-Steele level: out[b] = in[b] + M @ in[b-stride]; block 256 fuses next squaring
__global__ __launch_bounds__(256) void k_scan(const float* __restrict__ Vin,
                                              float* __restrict__ Vout,
                                              const float* __restrict__ M,
                                              int stride,
                                              const float* __restrict__ sq_in,
                                              float* __restrict__ sq_out)
{
  if (blockIdx.x == 256) { if (sq_out) matsq_block(sq_in, sq_out); return; }
  const int b = blockIdx.x >> 1, h = blockIdx.x & 1;
  const int tid = threadIdx.x;
  const int q = rfl(tid >> 6);
  const int r = tid & 63;
  const int gr = h*64 + r;
  const size_t colb = (size_t)SX*RC;
  if (b < stride) {
    const float* src = Vin + b*colb + (size_t)(q*16)*RC + gr;
    float* dst = Vout + b*colb + (size_t)(q*16)*RC + gr;
    #pragma unroll
    for (int jj = 0; jj < 16; jj++) dst[(size_t)jj*RC] = src[(size_t)jj*RC];
    return;
  }
  __shared__ float xs[64*64];
  const float* sp = Vin + (size_t)(b - stride)*colb + h*64 + r;
  #pragma unroll
  for (int jj = 0; jj < 16; jj++) { const int j = q*16 + jj; xs[j*64 + r] = sp[(size_t)j*RC]; }
  __syncthreads();
  float acc[16];
  const float* vb = Vin + (size_t)b*colb + (size_t)(q*16)*RC + gr;
  #pragma unroll
  for (int jj = 0; jj < 16; jj++) acc[jj] = vb[(size_t)jj*RC];
  for (int j = 0; j < 64; j++) {
    const float xj = xs[j*64 + r];
    const float* mr = M + j*64 + q*16;
    #pragma unroll
    for (int jj = 0; jj < 16; jj++) acc[jj] += mr[jj] * xj;
  }
  float* o = Vout + (size_t)b*colb + (size_t)(q*16)*RC + gr;
  #pragma unroll
  for (int jj = 0; jj < 16; jj++) o[(size_t)jj*RC] = acc[jj];
}

// replay chunk-local recurrence from boundary state; emit X (pre-update) and Y
__global__ __launch_bounds__(256) void k_phase3(const float* __restrict__ u,
                                                const float* __restrict__ Z,
                                                const float* __restrict__ AYtq,
                                                const float* __restrict__ Butq,
                                                float* __restrict__ Yout,
                                                float* __restrict__ Xout)
{
  __shared__ float xs[64*64];
  const int tid = threadIdx.x;
  const int q = rfl(tid >> 6);
  const int r = tid & 63;
  const int c = blockIdx.x >> 1;
  const int h = blockIdx.x & 1;
  const int gr = h*64 + r;

  if (c == 0) {
    #pragma unroll
    for (int jj = 0; jj < 16; jj++) xs[(q*16+jj)*64 + r] = 0.f;
  } else {
    const float* zsrc = Z + ((size_t)(c-1)*SX + q*16)*RC + gr;
    #pragma unroll
    for (int jj = 0; jj < 16; jj++) xs[(q*16+jj)*64 + r] = zsrc[(size_t)jj*RC];
  }
  __syncthreads();

  const float* uc = u + (size_t)c*LCH*SU*RC + gr;
  float* xo = Xout + (size_t)c*LCH*SX*RC + gr;
  float* yo = Yout + (size_t)c*LCH*SY*RC + gr;
  const float* bq = Butq + q*20;

  float ucur[4];
  #pragma unroll
  for (int ch = 0; ch < 4; ch++) ucur[ch] = uc[(size_t)ch*RC];

  for (int t = 0; t < LCH; t++) {
    float unxt[4] = {0.f, 0.f, 0.f, 0.f};
    if (t < LCH-1) {
      #pragma unroll
      for (int ch = 0; ch < 4; ch++) unxt[ch] = uc[(size_t)((t+1)*SU + ch)*RC];
    }
    float acc[17];
    #pragma unroll
    for (int jj = 0; jj < 17; jj++)
      acc[jj] = bq[jj]*ucur[0] + bq[80+jj]*ucur[1] + bq[160+jj]*ucur[2] + bq[240+jj]*ucur[3];

    #pragma unroll
    for (int jb = 0; jb < 4; jb++) {
      const bool mine = (jb == q);
      #pragma unroll
      for (int j2 = 0; j2 < 16; j2++) {
        const int j = jb*16 + j2;
        const float xj = xs[j*64 + r];
        if (mine) xo[((size_t)t*SX + j)*RC] = xj;      // X_k (pre-update)
        const float* ay = AYtq + (j*4 + q)*20;
        #pragma unroll
        for (int jj = 0; jj < 17; jj++) acc[jj] += ay[jj] * xj;
      }
    }
    __syncthreads();
    #pragma unroll
    for (int jj = 0; jj < 17; jj++) {
      const int i = q*17 + jj;
      if (i < SX) xs[i*64 + r] = acc[jj];
      else        yo[((size_t)t*SY + (i-SX))*RC] = acc[jj];
    }
    __syncthreads();
    #pragma unroll
    for (int ch = 0; ch < 4; ch++) ucur[ch] = unxt[ch];
  }
}

extern "C" void kernel_launch(void* const* d_in, const int* in_sizes, int n_in,
                              void* d_out, int out_size, void* d_ws, size_t ws_size,
                              hipStream_t stream)
{
  const float* u   = (const float*)d_in[0];
  const float* A   = (const float*)d_in[1];
  const float* Bu  = (const float*)d_in[2];
  const float* Cy  = (const float*)d_in[3];
  const float* Dyu = (const float*)d_in[4];
  float* ws   = (float*)d_ws;
  float* Yout = (float*)d_out;
  float* Xout = Yout + (size_t)NT*SY*RC;

  float* Mst  = ws + OFF_MST;
  float* AYtq = ws + OFF_AYTQ;
  float* Butq = ws + OFF_BUTQ;
  float* Kt   = ws + OFF_KT;
  float* V0   = ws + OFF_V0;
  float* V1   = ws + OFF_V1;

  hipLaunchKernelGGL(k_setup, dim3(1), dim3(256), 0, stream, A, Bu, Cy, Dyu, ws);
  hipLaunchKernelGGL(k_contrib, dim3(257), dim3(256), 0, stream, u, Kt, V0, Mst, Mst + 4096);

  float* vin = V0; float* vout = V1;
  for (int s = 0; s < 7; s++) {
    const float* sqi = (s <= 4) ? (const float*)(Mst + (s+1)*4096) : nullptr;
    float*       sqo = (s <= 4) ? (Mst + (s+2)*4096) : nullptr;
    hipLaunchKernelGGL(k_scan, dim3(257), dim3(256), 0, stream,
                       (const float*)vin, vout, (const float*)(Mst + s*4096), 1 << s, sqi, sqo);
    float* t = vin; vin = vout; vout = t;
  }
  // after 7 levels result is in vin (= V1)
  hipLaunchKernelGGL(k_phase3, dim3(256), dim3(256), 0, stream,
                     u, (const float*)vin, (const float*)AYtq, (const float*)Butq, Yout, Xout);
}

// Round 2
// 775.442 us; speedup vs baseline: 3.8245x; 3.8245x over previous
//
#include <hip/hip_runtime.h>
#include <cstddef>

// Linear SSM via chunked GEMM on MFMA (split-bf16 for fp32-grade accuracy):
//   chunk L=16, C=512.  X_{c,t} = A^t Z_{c-1} + sum_{tau<t} A^{t-1-tau} B u_tau
//   => Out_c (1152x128, 72 padded rows per t: 64 X + 4 Y + 4 pad) = W @ [Z_{c-1}; U_c]
//   Z boundaries via MFMA Hillis-Steele scan (9 levels, M = (A^16)^(2^s)).
//   Split trick: v = hi + lo (two bf16); W@S ~= Wh Sh + Wh Sl + Wl Sh  (~2^-16 rel).

typedef unsigned short u16;
typedef unsigned int u32;
typedef __bf16 bf16x8 __attribute__((ext_vector_type(8)));
typedef float f32x4 __attribute__((ext_vector_type(4)));

#define NT 8192
#define RC 128
#define LCH 16
#define CCH 512
#define NMT 9      // m-tiles of 128 per chunk (1152 rows)
#define GW 72      // padded rows per timestep (64 X + 4 Y + 4 pad)

// ---- ws layout ----
// fp32 region (float offsets)
#define OFF_POWS 0          // 17*4096 : P[t] = A^t
#define OFF_Q    69632      // 17*256  : Q[d] = A^d B
#define OFF_R    73984      // 17*256  : R[t] = C A^t
#define OFF_CQ   78336      // 17*16   : CQ[d] = C A^d B
#define OFF_KHF  78608      // 4096    : Khat fp32
#define OFF_MS   82704      // 9*4096  : Mscan[s] = (A^16)^(2^s) fp32
// u16 regions (byte offsets)
#define B_MSH 478720        // 9*4096*2
#define B_MSL 552448
#define B_KHH 626176        // 4096*2
#define B_KHL 634368
#define B_WH  642560        // 1152*128*2
#define B_WL  937472
// fp32 V ping-pong buffers (float offsets)
#define OFF_V0 308096       // 512*8192
#define OFF_V1 4502400

// XOR swizzle within a 64-element k-extent (u16 tiles), 16B groups
#define SWZ_K(r,k) (((((k) >> 3) ^ ((r) & 7)) << 3) | ((k) & 7))

static __device__ __forceinline__ u16 f2bf(float v) {
  union { float f; u32 u; } x; x.f = v;
  u32 r = x.u + 0x7fffu + ((x.u >> 16) & 1u);
  return (u16)(r >> 16);
}
static __device__ __forceinline__ float bf2f(u16 h) {
  union { float f; u32 u; } x; x.u = ((u32)h) << 16; return x.f;
}
static __device__ __forceinline__ void split_bf(float v, u16& h, u16& l) {
  h = f2bf(v);
  l = f2bf(v - bf2f(h));
}

// ---------- setup: matrix powers and derived coefficient tables ----------
__global__ __launch_bounds__(1024) void k_setup(const float* __restrict__ A,
                                                const float* __restrict__ Bu,
                                                const float* __restrict__ Cy,
                                                float* __restrict__ ws)
{
  float* P  = ws + OFF_POWS;
  float* Q  = ws + OFF_Q;
  float* R  = ws + OFF_R;
  float* CQ = ws + OFF_CQ;
  float* Kf = ws + OFF_KHF;
  float* Ms = ws + OFF_MS;
  const int tid = threadIdx.x;

  for (int e = tid; e < 4096; e += 1024) {
    P[e] = ((e >> 6) == (e & 63)) ? 1.f : 0.f;   // P0 = I
    P[4096 + e] = A[e];                           // P1 = A
  }
  __syncthreads();

  // doubling: for base in {1,2,4,8}: P[base+1+x] = P[base] @ P[x+1], x=0..base-1
  for (int base = 1; base <= 8; base <<= 1) {
    int nout = base * 1024;   // (base*4096)/4 outputs of width 4
    for (int o = tid; o < nout; o += 1024) {
      int x  = o >> 10;
      int ij = o & 1023;
      int i  = ij >> 4, j4 = (ij & 15) * 4;
      const float* L  = P + (size_t)base * 4096 + i * 64;
      const float* Rm = P + (size_t)(x + 1) * 4096;
      float a0 = 0, a1 = 0, a2 = 0, a3 = 0;
      for (int k = 0; k < 64; k++) {
        float lv = L[k];
        const float* rp = Rm + k * 64 + j4;
        a0 += lv * rp[0]; a1 += lv * rp[1]; a2 += lv * rp[2]; a3 += lv * rp[3];
      }
      float* Ot = P + (size_t)(base + 1 + x) * 4096 + i * 64 + j4;
      Ot[0] = a0; Ot[1] = a1; Ot[2] = a2; Ot[3] = a3;
    }
    __syncthreads();
  }

  // Q[d] = P_d @ Bu   (17 x 64 x 4)
  for (int o = tid; o < 17 * 256; o += 1024) {
    int d = o >> 8, i = (o >> 2) & 63, ch = o & 3;
    const float* Pd = P + (size_t)d * 4096;
    float acc = 0.f;
    for (int k = 0; k < 64; k++) acc += Pd[i * 64 + k] * Bu[k * 4 + ch];
    Q[o] = acc;
  }
  // R[t] = Cy @ P_t   (17 x 4 x 64)
  for (int o = tid; o < 17 * 256; o += 1024) {
    int t = o >> 8, y = (o >> 6) & 3, j = o & 63;
    const float* Pt = P + (size_t)t * 4096;
    float acc = 0.f;
    for (int k = 0; k < 64; k++) acc += Cy[y * 64 + k] * Pt[k * 64 + j];
    R[o] = acc;
  }
  __syncthreads();
  // CQ[d] = Cy @ Q_d  (17 x 4 x 4)
  for (int o = tid; o < 17 * 16; o += 1024) {
    int d = o >> 4, y = (o >> 2) & 3, ch = o & 3;
    const float* Qd = Q + d * 256;
    float acc = 0.f;
    for (int k = 0; k < 64; k++) acc += Cy[y * 64 + k] * Qd[k * 4 + ch];
    CQ[o] = acc;
  }
  // Khat[i][4*tau+ch] = Q[15-tau][i][ch]
  for (int o = tid; o < 4096; o += 1024) {
    int i = o >> 6, kk = o & 63, tau = kk >> 2, ch = kk & 3;
    Kf[o] = Q[(15 - tau) * 256 + i * 4 + ch];
  }
  // Mscan[0] = P16
  for (int e = tid; e < 4096; e += 1024) Ms[e] = P[16 * 4096 + e];
}

// ---------- build split-bf16 W, Khat, Mscan0 (pre-swizzled global layout) ----------
__global__ __launch_bounds__(256) void k_wbuild(float* __restrict__ ws,
                                                const float* __restrict__ Dyu)
{
  const float* P  = ws + OFF_POWS;
  const float* Q  = ws + OFF_Q;
  const float* R  = ws + OFF_R;
  const float* CQ = ws + OFF_CQ;
  const float* Kf = ws + OFF_KHF;
  const float* Ms = ws + OFF_MS;
  u16* Wh  = (u16*)((char*)ws + B_WH);
  u16* Wl  = (u16*)((char*)ws + B_WL);
  u16* KhH = (u16*)((char*)ws + B_KHH);
  u16* KhL = (u16*)((char*)ws + B_KHL);
  u16* MsH = (u16*)((char*)ws + B_MSH);
  u16* MsL = (u16*)((char*)ws + B_MSL);

  int idx = blockIdx.x * 256 + threadIdx.x;
  if (idx < 1152 * 128) {
    int m = idx >> 7, kk = idx & 127;
    int t = m / GW, i = m - t * GW;
    float v = 0.f;
    if (i < 68) {
      if (kk < 64) {
        v = (i < 64) ? P[(size_t)t * 4096 + i * 64 + kk]
                     : R[t * 256 + (i - 64) * 64 + kk];
      } else {
        int tau = (kk - 64) >> 2, ch = (kk - 64) & 3;
        if (tau < t)
          v = (i < 64) ? Q[(t - 1 - tau) * 256 + i * 4 + ch]
                       : CQ[(t - 1 - tau) * 16 + (i - 64) * 4 + ch];
        else if (tau == t && i >= 64)
          v = Dyu[(i - 64) * 4 + ch];
      }
    }
    u16 h, l; split_bf(v, h, l);
    int off = m * 128 + (kk & 64) + SWZ_K(m, kk & 63);
    Wh[off] = h; Wl[off] = l;
  } else if (idx < 1152 * 128 + 4096) {
    int e = idx - 1152 * 128, i = e >> 6, k = e & 63;
    u16 h, l; split_bf(Kf[e], h, l);
    KhH[i * 64 + SWZ_K(i, k)] = h;
    KhL[i * 64 + SWZ_K(i, k)] = l;
  } else if (idx < 1152 * 128 + 8192) {
    int e = idx - 1152 * 128 - 4096, i = e >> 6, k = e & 63;
    u16 h, l; split_bf(Ms[e], h, l);
    MsH[i * 64 + SWZ_K(i, k)] = h;
    MsL[i * 64 + SWZ_K(i, k)] = l;
  }
}

// ---------- shared MFMA core: out(64x128) = M(64x64) @ X(64x128) [+ add] ----------
__device__ void mfma_apply64(const u16* __restrict__ MhG, const u16* __restrict__ MlG,
                             const float* __restrict__ X, const float* __restrict__ addsrc,
                             float* __restrict__ out)
{
  __shared__ __align__(16) u16 sMh[4096], sMl[4096];
  __shared__ __align__(16) u16 sXh[8192], sXl[8192];
  const int tid = threadIdx.x;
  // stage M (pre-swizzled, straight copy)
  for (int e = tid; e < 2048; e += 256) {
    ((u32*)sMh)[e] = ((const u32*)MhG)[e];
    ((u32*)sMl)[e] = ((const u32*)MlG)[e];
  }
  // stage X transposed + split: LDS [n][k] swizzled
  for (int it = 0; it < 16; it++) {
    int idx = it * 256 + tid;
    int n = idx & 127, kk = (idx >> 7) * 2;
    float f0 = X[(size_t)kk * 128 + n];
    float f1 = X[(size_t)(kk + 1) * 128 + n];
    u16 h0, l0, h1, l1;
    split_bf(f0, h0, l0); split_bf(f1, h1, l1);
    int off = n * 64 + SWZ_K(n, kk);
    *(u32*)&sXh[off] = (u32)h0 | ((u32)h1 << 16);
    *(u32*)&sXl[off] = (u32)l0 | ((u32)l1 << 16);
  }
  __syncthreads();

  const int w = tid >> 6, lane = tid & 63, m16 = lane & 15, q = lane >> 4;
  f32x4 zero = {0.f, 0.f, 0.f, 0.f};
  f32x4 acc[4][2];
  for (int a = 0; a < 4; a++) for (int b = 0; b < 2; b++) acc[a][b] = zero;

  for (int prod = 0; prod < 3; prod++) {
    const u16* As = (prod == 2) ? sMl : sMh;
    const u16* Bs = (prod == 1) ? sXl : sXh;
    #pragma unroll
    for (int ks = 0; ks < 2; ks++) {
      const int kg = ks * 4 + q;
      bf16x8 bfr[2];
      #pragma unroll
      for (int fn = 0; fn < 2; fn++) {
        int n = w * 32 + fn * 16 + m16;
        bfr[fn] = *(const bf16x8*)&Bs[n * 64 + ((kg ^ (n & 7)) << 3)];
      }
      #pragma unroll
      for (int fm = 0; fm < 4; fm++) {
        int r = fm * 16 + m16;
        bf16x8 afr = *(const bf16x8*)&As[r * 64 + ((kg ^ (r & 7)) << 3)];
        #pragma unroll
        for (int fn = 0; fn < 2; fn++)
          acc[fm][fn] = __builtin_amdgcn_mfma_f32_16x16x32_bf16(afr, bfr[fn], acc[fm][fn], 0, 0, 0);
      }
    }
  }
  #pragma unroll
  for (int fm = 0; fm < 4; fm++)
    #pragma unroll
    for (int fn = 0; fn < 2; fn++)
      #pragma unroll
      for (int rg = 0; rg < 4; rg++) {
        int row = fm * 16 + q * 4 + rg;
        int col = w * 32 + fn * 16 + m16;
        float v = acc[fm][fn][rg];
        if (addsrc) v += addsrc[(size_t)row * 128 + col];
        out[(size_t)row * 128 + col] = v;
      }
}

// ---------- fused 64x64 fp32 square + split-swizzled bf16 write ----------
__device__ void matsq_split(const float* __restrict__ Min, float* __restrict__ Mout,
                            u16* __restrict__ oH, u16* __restrict__ oL)
{
  __shared__ float Pm[64 * 65];
  const int tid = threadIdx.x;
  for (int e = tid; e < 4096; e += 256) Pm[(e >> 6) * 65 + (e & 63)] = Min[e];
  __syncthreads();
  const int it = tid >> 4, jt = tid & 15;
  float acc[4][4] = {};
  for (int k = 0; k < 64; k++) {
    float a[4], b[4];
    #pragma unroll
    for (int ii = 0; ii < 4; ii++) a[ii] = Pm[(it * 4 + ii) * 65 + k];
    #pragma unroll
    for (int jj = 0; jj < 4; jj++) b[jj] = Pm[k * 65 + jt * 4 + jj];
    #pragma unroll
    for (int ii = 0; ii < 4; ii++)
      #pragma unroll
      for (int jj = 0; jj < 4; jj++) acc[ii][jj] += a[ii] * b[jj];
  }
  #pragma unroll
  for (int ii = 0; ii < 4; ii++)
    #pragma unroll
    for (int jj = 0; jj < 4; jj++) {
      int r = it * 4 + ii, c = jt * 4 + jj;
      float v = acc[ii][jj];
      Mout[r * 64 + c] = v;
      u16 h, l; split_bf(v, h, l);
      oH[r * 64 + SWZ_K(r, c)] = h;
      oL[r * 64 + SWZ_K(r, c)] = l;
    }
}

// ---------- contrib: w_c = Khat @ U_c ----------
__global__ __launch_bounds__(256) void k_contrib(const float* __restrict__ u,
                                                 const u16* __restrict__ KhH,
                                                 const u16* __restrict__ KhL,
                                                 float* __restrict__ V0)
{
  int b = blockIdx.x;
  mfma_apply64(KhH, KhL, u + (size_t)b * 8192, nullptr, V0 + (size_t)b * 8192);
}

// ---------- scan level: out[b] = in[b] + M_s @ in[b-stride] ----------
__global__ __launch_bounds__(256) void k_scan(const float* __restrict__ Vin,
                                              float* __restrict__ Vout, int stride,
                                              const u16* __restrict__ MsH,
                                              const u16* __restrict__ MsL,
                                              const float* __restrict__ sq_in,
                                              float* __restrict__ sq_out,
                                              u16* __restrict__ sqH, u16* __restrict__ sqL)
{
  int b = blockIdx.x;
  if (b >= CCH) { if (sq_out) matsq_split(sq_in, sq_out, sqH, sqL); return; }
  if (b < stride) {
    const float4* src = (const float4*)(Vin + (size_t)b * 8192);
    float4* dst = (float4*)(Vout + (size_t)b * 8192);
    for (int e = threadIdx.x; e < 2048; e += 256) dst[e] = src[e];
    return;
  }
  mfma_apply64(MsH, MsL, Vin + (size_t)(b - stride) * 8192,
               Vin + (size_t)b * 8192, Vout + (size_t)b * 8192);
}

// ---------- main GEMM: Out_c = W @ [Z_{c-1}; U_c], split-bf16 x3 ----------
__global__ __launch_bounds__(256) void k_gemm(const float* __restrict__ u,
                                              const float* __restrict__ Z,
                                              const u16* __restrict__ Wh,
                                              const u16* __restrict__ Wl,
                                              float* __restrict__ Yout,
                                              float* __restrict__ Xout)
{
  __shared__ __align__(16) u16 sWh[8192], sWl[8192];
  __shared__ __align__(16) u16 sSh[8192], sSl[8192];
  const int bid = blockIdx.x;
  const int c = bid / NMT, mt = bid - c * NMT;
  const int tid = threadIdx.x;
  const int w = tid >> 6, lane = tid & 63, m16 = lane & 15, q = lane >> 4;
  const int wm = w >> 1, wn = w & 1;

  f32x4 zero = {0.f, 0.f, 0.f, 0.f};
  f32x4 acc[4][4];
  for (int a = 0; a < 4; a++) for (int b = 0; b < 4; b++) acc[a][b] = zero;

  for (int H = 0; H < 2; H++) {
    if (H) __syncthreads();
    // stage W K-half (pre-swizzled rows, straight 16B copies)
    for (int e = tid; e < 1024; e += 256) {
      int m_loc = e >> 3, seg = e & 7;
      size_t goff = (size_t)(mt * 128 + m_loc) * 128 + H * 64 + seg * 8;
      ((uint4*)sWh)[e] = *(const uint4*)(Wh + goff);
      ((uint4*)sWl)[e] = *(const uint4*)(Wl + goff);
    }
    // stage S K-half: rows 0..63 = Z_{c-1}, rows 64..127 = U_c; transpose+split
    for (int it = 0; it < 16; it++) {
      int idx = it * 256 + tid;
      int n = idx & 127, k = (idx >> 7) * 2;
      int kkg = H * 64 + k;
      float f0, f1;
      if (kkg < 64) {
        f0 = (c == 0) ? 0.f : Z[((size_t)(c - 1) * 64 + kkg) * 128 + n];
        f1 = (c == 0) ? 0.f : Z[((size_t)(c - 1) * 64 + kkg + 1) * 128 + n];
      } else {
        f0 = u[((size_t)c * 64 + (kkg - 64)) * 128 + n];
        f1 = u[((size_t)c * 64 + (kkg - 63)) * 128 + n];
      }
      u16 h0, l0, h1, l1;
      split_bf(f0, h0, l0); split_bf(f1, h1, l1);
      int off = n * 64 + SWZ_K(n, k);
      *(u32*)&sSh[off] = (u32)h0 | ((u32)h1 << 16);
      *(u32*)&sSl[off] = (u32)l0 | ((u32)l1 << 16);
    }
    __syncthreads();

    for (int prod = 0; prod < 3; prod++) {
      const u16* As = (prod == 2) ? sWl : sWh;
      const u16* Bs = (prod == 1) ? sSl : sSh;
      #pragma unroll
      for (int ks = 0; ks < 2; ks++) {
        const int kg = ks * 4 + q;
        bf16x8 bfr[4];
        #pragma unroll
        for (int fn = 0; fn < 4; fn++) {
          int n = wn * 64 + fn * 16 + m16;
          bfr[fn] = *(const bf16x8*)&Bs[n * 64 + ((kg ^ (n & 7)) << 3)];
        }
        #pragma unroll
        for (int fm = 0; fm < 4; fm++) {
          int r = wm * 64 + fm * 16 + m16;
          bf16x8 afr = *(const bf16x8*)&As[r * 64 + ((kg ^ (r & 7)) << 3)];
          #pragma unroll
          for (int fn = 0; fn < 4; fn++)
            acc[fm][fn] = __builtin_amdgcn_mfma_f32_16x16x32_bf16(afr, bfr[fn], acc[fm][fn], 0, 0, 0);
        }
      }
    }
  }
  // epilogue: scatter rows (t,i) -> X / Y
  #pragma unroll
  for (int fm = 0; fm < 4; fm++)
    #pragma unroll
    for (int fn = 0; fn < 4; fn++)
      #pragma unroll
      for (int rg = 0; rg < 4; rg++) {
        unsigned m_loc = wm * 64 + fm * 16 + q * 4 + rg;
        unsigned m = mt * 128 + m_loc;
        unsigned t = m / GW;
        unsigned i = m - t * GW;
        int col = wn * 64 + fn * 16 + m16;
        float v = acc[fm][fn][rg];
        size_t nt_ = (size_t)c * LCH + t;
        if (i < 64) Xout[(nt_ * 64 + i) * 128 + col] = v;
        else if (i < 68) Yout[(nt_ * 4 + (i - 64)) * 128 + col] = v;
      }
}

extern "C" void kernel_launch(void* const* d_in, const int* in_sizes, int n_in,
                              void* d_out, int out_size, void* d_ws, size_t ws_size,
                              hipStream_t stream)
{
  const float* u   = (const float*)d_in[0];
  const float* A   = (const float*)d_in[1];
  const float* Bu  = (const float*)d_in[2];
  const float* Cy  = (const float*)d_in[3];
  const float* Dyu = (const float*)d_in[4];
  float* ws = (float*)d_ws;
  float* Yout = (float*)d_out;
  float* Xout = Yout + (size_t)NT * 4 * RC;

  u16* MsH = (u16*)((char*)d_ws + B_MSH);
  u16* MsL = (u16*)((char*)d_ws + B_MSL);
  u16* KhH = (u16*)((char*)d_ws + B_KHH);
  u16* KhL = (u16*)((char*)d_ws + B_KHL);
  u16* Wh  = (u16*)((char*)d_ws + B_WH);
  u16* Wl  = (u16*)((char*)d_ws + B_WL);
  float* Ms = ws + OFF_MS;
  float* V0 = ws + OFF_V0;
  float* V1 = ws + OFF_V1;

  hipLaunchKernelGGL(k_setup, dim3(1), dim3(1024), 0, stream, A, Bu, Cy, ws);
  hipLaunchKernelGGL(k_wbuild, dim3(608), dim3(256), 0, stream, ws, Dyu);
  hipLaunchKernelGGL(k_contrib, dim3(CCH), dim3(256), 0, stream, u, KhH, KhL, V0);

  float* vin = V0; float* vout = V1;
  for (int s = 0; s < 9; s++) {
    const float* sqi = (s < 8) ? (const float*)(Ms + s * 4096) : nullptr;
    float* sqo       = (s < 8) ? (Ms + (s + 1) * 4096) : nullptr;
    hipLaunchKernelGGL(k_scan, dim3(CCH + 1), dim3(256), 0, stream,
                       (const float*)vin, vout, 1 << s,
                       MsH + s * 4096, MsL + s * 4096,
                       sqi, sqo, MsH + (s + 1) * 4096, MsL + (s + 1) * 4096);
    float* t = vin; vin = vout; vout = t;
  }
  hipLaunchKernelGGL(k_gemm, dim3(CCH * NMT), dim3(256), 0, stream,
                     u, (const float*)vin, Wh, Wl, Yout, Xout);
}